// Round 16
// baseline (135.444 us; speedup 1.0000x reference)
//
#include <hip/hip_runtime.h>

#define NHEADS 16
#define NW 8
#define SEQ 1024
#define BATCH 8
#define EMB 128

typedef _Float16 half2_t __attribute__((ext_vector_type(2)));
typedef _Float16 half4_t __attribute__((ext_vector_type(4)));
typedef _Float16 half8_t __attribute__((ext_vector_type(8)));
typedef float    f32x4   __attribute__((ext_vector_type(4)));
typedef int      i32x2   __attribute__((ext_vector_type(2)));

__device__ __forceinline__ half2_t pkrtz(float a, float b) {
    return __builtin_bit_cast(half2_t, __builtin_amdgcn_cvt_pkrtz(a, b));
}

#if __has_builtin(__builtin_amdgcn_permlane16_swap)
#define HAVE_PLSWAP 1
#else
#define HAVE_PLSWAP 0
#endif

// qattn LDS (halves): kvhT [8 dims][stride 1042] @0 (dword stride 521 == 9 mod 32,
// so the 8 V-rows hit disjoint banks), ones@8336, zero@8344, slack to 8448
// (covers last-iter V prefetch overrun: max 8339).
#define KVT_STR   1042
#define ONES_OFF  (8 * KVT_STR)            // 8336
#define ZERO_OFF  (ONES_OFF + 8)           // 8344
#define SMEM_H    8448

// quantum_heads closed form for one (b,s,head) row (fp32 input):
// c[w] = cos(x[w] + theta[w]); z[0] = c1..c7; z[w>=1] = c0..cw
__device__ __forceinline__ void qrow(const float* __restrict__ xp,
                                     const float* __restrict__ th, float* z) {
    float4 a = *reinterpret_cast<const float4*>(xp);
    float4 b = *reinterpret_cast<const float4*>(xp + 4);
    float c0 = __cosf(a.x + th[0]);
    float c1 = __cosf(a.y + th[1]);
    float c2 = __cosf(a.z + th[2]);
    float c3 = __cosf(a.w + th[3]);
    float c4 = __cosf(b.x + th[4]);
    float c5 = __cosf(b.y + th[5]);
    float c6 = __cosf(b.z + th[6]);
    float c7 = __cosf(b.w + th[7]);
    float u = c1 * c2;
    u *= c3; u *= c4; u *= c5; u *= c6; u *= c7;
    z[0] = u;
    z[1] = c0 * c1;
    z[2] = z[1] * c2;
    z[3] = z[2] * c3;
    z[4] = z[3] * c4;
    z[5] = z[4] * c5;
    z[6] = z[5] * c6;
    z[7] = z[6] * c7;
}

// Pre-kernel: H[row][h*8+d] = f16(quantum_heads(x)[row, h, d]).  One (row,head)
// per thread, fully coalesced. grid = 131072/256 = 512 blocks.
__global__ __launch_bounds__(256) void qheads(
    const float* __restrict__ x,
    const float* __restrict__ theta,
    _Float16* __restrict__ H)
{
    const int g   = blockIdx.x * 256 + threadIdx.x;
    const int row = g >> 4, h = g & 15;
    float th[8];
#pragma unroll
    for (int w = 0; w < 8; ++w) th[w] = theta[w];
    float z[8];
    qrow(x + (size_t)row * EMB + h * NW, th, z);
    half8_t hv;
#pragma unroll
    for (int d = 0; d < 8; ++d) hv[d] = (_Float16)z[d];
    *reinterpret_cast<half8_t*>(H + (size_t)row * EMB + h * NW) = hv;
}

// MFMA attention v2: K/Q fragments straight from global H (quads!=0 of the K
// A-frag carry garbage — safe, because the Q B-frag is zero there, and H is
// always finite). LDS holds only the transposed V plane. qsplit=16 ->
// grid = 128 bh * 16 = 2048 blocks, 8 blocks/CU (32 waves/CU).
__global__ __launch_bounds__(256, 8) void qattn_mfma(
    const _Float16* __restrict__ H,
    __fp16* __restrict__ P)        // [B*S][128] f16, normalized attn@h
{
    __shared__ __align__(16) _Float16 smem[SMEM_H];
    const int t   = threadIdx.x;
    const int bid = blockIdx.x;
    const int qs  = bid & 15;               // query 1/16th (64 q)
    const int bh  = bid >> 4;               // 0..127
    const int b   = bh >> 4, h = bh & 15;

    // ---- stage transposed V plane from H (cheap copy + scalar transpose) ----
#pragma unroll
    for (int i = 0; i < 4; ++i) {
        const int kl = t + 256 * i;
        half8_t hv = *reinterpret_cast<const half8_t*>(
            H + (size_t)(b * SEQ + kl) * EMB + h * NW);
#pragma unroll
        for (int d = 0; d < 8; ++d) smem[d * KVT_STR + kl] = hv[d];
    }
    if (t < 8)              smem[ONES_OFF + t]     = (_Float16)1.0f;
    else if (t < 16)        smem[ZERO_OFF + t - 8] = (_Float16)0.0f;
    __syncthreads();

    const int lane = t & 63;
    const int wv   = t >> 6;
    const int q16  = lane & 15;
    const int qd   = lane >> 4;             // quad 0..3
    const int qbase = qs * 64 + wv * 16;

    // ---- Q fragment (B operand) from global H; quads!=0 ZERO (this zeroing
    // is what makes the garbage-K trick valid) ----
    const _Float16 QSh = (_Float16)0.51012924f;   // (1/sqrt(8))*log2(e)
    half8_t qfrag = {};
    if (qd == 0) {
        half8_t qv = *reinterpret_cast<const half8_t*>(
            H + (size_t)(b * SEQ + qbase + q16) * EMB + h * NW);
#pragma unroll
        for (int j = 0; j < 8; ++j) qfrag[j] = qv[j] * QSh;
    }

    // ---- K A-frag global pointers (all lanes load; quads duplicate quad0) ----
    const _Float16* pK = H + (size_t)(b * SEQ + q16) * EMB + h * NW;
    // kB at +16 rows = 2048 halves; step per 32 keys = 4096 halves

    // V-operand dword loads from LDS; key order kappa matches permlane output.
    const unsigned int* vb; int vo0, vo1, vo2, vo3; int vstep;
    if (q16 < 8) {
        vb = reinterpret_cast<const unsigned int*>(&smem[q16 * KVT_STR]);
#if HAVE_PLSWAP
        const int bo = (qd & 1) + (qd >> 1) * 4;
        vo0 = bo; vo1 = bo + 2; vo2 = bo + 8; vo3 = bo + 10;
#else
        vo0 = qd * 4; vo1 = vo0 + 1; vo2 = vo0 + 2; vo3 = vo0 + 3;
#endif
        vstep = 16;                                // 32 keys = 16 dwords
    } else if (q16 == 8) {
        vb = reinterpret_cast<const unsigned int*>(&smem[ONES_OFF]);
        vo0 = vo1 = vo2 = vo3 = 0; vstep = 0;
    } else {
        vb = reinterpret_cast<const unsigned int*>(&smem[ZERO_OFF]);
        vo0 = vo1 = vo2 = vo3 = 0; vstep = 0;
    }

#if !HAVE_PLSWAP
    const bool oddq = (qd & 1);
    const bool hiC  = (qd >= 2);
    const int  iA   = (q16 + (qd & 1) * 32 + (qd >> 1) * 16) * 4;
    const int  iB   = iA ^ 64;
#endif
    const int  lidx = (32 + q16) * 4;              // lane holding dim-8 row (l)

    f32x4 oacc = {0.f, 0.f, 0.f, 0.f};
    const f32x4 zc = {0.f, 0.f, 0.f, 0.f};

    half8_t kA = *reinterpret_cast<const half8_t*>(pK);
    half8_t kB = *reinterpret_cast<const half8_t*>(pK + 2048);
    unsigned int v0 = vb[vo0], v1 = vb[vo1], v2 = vb[vo2], v3 = vb[vo3];

    for (int kt = 0; kt < 32; ++kt) {
        pK += 4096; vb += vstep;
        half8_t nkA = *reinterpret_cast<const half8_t*>(pK);        // prefetch
        half8_t nkB = *reinterpret_cast<const half8_t*>(pK + 2048); // (overrun-
        unsigned int nv0 = vb[vo0], nv1 = vb[vo1];                  //  safe)
        unsigned int nv2 = vb[vo2], nv3 = vb[vo3];

        union { unsigned int i[4]; half8_t h; } vf;
        vf.i[0] = v0; vf.i[1] = v1; vf.i[2] = v2; vf.i[3] = v3;

        // S^T tiles: C[row=key=qd*4+reg][col=q=lane&15]
        f32x4 c0 = __builtin_amdgcn_mfma_f32_16x16x32_f16(kA, qfrag, zc, 0, 0, 0);
        f32x4 c1 = __builtin_amdgcn_mfma_f32_16x16x32_f16(kB, qfrag, zc, 0, 0, 0);
        half2_t p0 = pkrtz(__builtin_amdgcn_exp2f(c0[0]), __builtin_amdgcn_exp2f(c0[1]));
        half2_t p1 = pkrtz(__builtin_amdgcn_exp2f(c0[2]), __builtin_amdgcn_exp2f(c0[3]));
        half2_t p2 = pkrtz(__builtin_amdgcn_exp2f(c1[0]), __builtin_amdgcn_exp2f(c1[1]));
        half2_t p3 = pkrtz(__builtin_amdgcn_exp2f(c1[2]), __builtin_amdgcn_exp2f(c1[3]));
        union { half2_t h; int i; } u0, u1, u2, u3;
        u0.h = p0; u1.h = p1; u2.h = p2; u3.h = p3;
        union { int i[4]; half8_t h; } bf;
#if HAVE_PLSWAP
        i32x2 s01 = __builtin_amdgcn_permlane16_swap(u0.i, u1.i, false, false);
        i32x2 s23 = __builtin_amdgcn_permlane16_swap(u2.i, u3.i, false, false);
        bf.i[0] = s01[0]; bf.i[1] = s01[1];
        bf.i[2] = s23[0]; bf.i[3] = s23[1];
#else
        const int a0 = oddq ? u2.i : u0.i;
        const int a1 = oddq ? u3.i : u1.i;
        const int a2 = oddq ? u0.i : u2.i;
        const int a3 = oddq ? u1.i : u3.i;
        const int r0 = __builtin_amdgcn_ds_bpermute(iA, a0);
        const int r1 = __builtin_amdgcn_ds_bpermute(iA, a1);
        const int r2 = __builtin_amdgcn_ds_bpermute(iB, a2);
        const int r3 = __builtin_amdgcn_ds_bpermute(iB, a3);
        bf.i[0] = hiC ? r2 : r0;
        bf.i[1] = hiC ? r3 : r1;
        bf.i[2] = hiC ? r0 : r2;
        bf.i[3] = hiC ? r1 : r3;
#endif
        // O^T += Vx^T . P^T  (ones col -> row-sum l in dim 8)
        oacc = __builtin_amdgcn_mfma_f32_16x16x32_f16(vf.h, bf.h, oacc, 0, 0, 0);

        kA = nkA; kB = nkB;
        v0 = nv0; v1 = nv1; v2 = nv2; v3 = nv3;
    }

    // ---- epilogue: normalize by l (row 8 = quad2 reg0), write P f16 ----
    {
        f32x4 c = oacc;
        const float lsum = __int_as_float(
            __builtin_amdgcn_ds_bpermute(lidx, __float_as_int(c[0])));
        const float inv = 1.0f / lsum;
        if (qd < 2) {                       // quads 0,1 hold dims 0-7
            half2_t w0 = pkrtz(c[0] * inv, c[1] * inv);
            half2_t w1 = pkrtz(c[2] * inv, c[3] * inv);
            half4_t o4; o4[0] = w0[0]; o4[1] = w0[1]; o4[2] = w1[0]; o4[3] = w1[1];
            const int row = b * SEQ + qbase + q16;
            *reinterpret_cast<half4_t*>(
                reinterpret_cast<_Float16*>(P) + (size_t)row * EMB + h * NW + qd * 4) = o4;
        }
    }
}

// MFMA projection with fused W f32->f16 conversion (R12-verified):
// out[row][e] = sum_f P[row][f]*W[e][f] + bias[e]. No LDS, no barriers.
__global__ __launch_bounds__(256) void proj_mfma(
    const __fp16* __restrict__ Pv,
    const float* __restrict__ W,
    const float* __restrict__ bias,
    float* __restrict__ out)
{
    const _Float16* P = reinterpret_cast<const _Float16*>(Pv);
    const int t    = threadIdx.x;
    const int lane = t & 63;
    const int wv   = t >> 6;
    const int n16  = lane & 15;
    const int qd   = lane >> 4;
    const int row0 = blockIdx.x * 16;
    const int col0 = wv * 32;

    half8_t a[4];
#pragma unroll
    for (int kb = 0; kb < 4; ++kb)
        a[kb] = *reinterpret_cast<const half8_t*>(
            P + (size_t)(row0 + n16) * EMB + kb * 32 + qd * 8);

    const f32x4 zc = {0.f, 0.f, 0.f, 0.f};
#pragma unroll
    for (int et = 0; et < 2; ++et) {
        const int e = col0 + et * 16 + n16;
        f32x4 acc = zc;
#pragma unroll
        for (int kb = 0; kb < 4; ++kb) {
            const float* wp = W + (size_t)e * EMB + kb * 32 + qd * 8;
            float4 w0 = *reinterpret_cast<const float4*>(wp);
            float4 w1 = *reinterpret_cast<const float4*>(wp + 4);
            half2_t h0 = pkrtz(w0.x, w0.y);
            half2_t h1 = pkrtz(w0.z, w0.w);
            half2_t h2 = pkrtz(w1.x, w1.y);
            half2_t h3 = pkrtz(w1.z, w1.w);
            half8_t bfr;
            bfr[0] = h0[0]; bfr[1] = h0[1]; bfr[2] = h1[0]; bfr[3] = h1[1];
            bfr[4] = h2[0]; bfr[5] = h2[1]; bfr[6] = h3[0]; bfr[7] = h3[1];
            acc = __builtin_amdgcn_mfma_f32_16x16x32_f16(a[kb], bfr, acc, 0, 0, 0);
        }
        const float bv = bias[e];
#pragma unroll
        for (int r = 0; r < 4; ++r)
            out[(size_t)(row0 + qd * 4 + r) * EMB + e] = acc[r] + bv;
    }
}

extern "C" void kernel_launch(void* const* d_in, const int* in_sizes, int n_in,
                              void* d_out, int out_size, void* d_ws, size_t ws_size,
                              hipStream_t stream)
{
    const float* x     = (const float*)d_in[0];
    const float* theta = (const float*)d_in[1];
    const float* W     = (const float*)d_in[2];
    const float* bias  = (const float*)d_in[3];
    float* out = (float*)d_out;

    _Float16* H  = (_Float16*)d_ws;                          // 2 MB
    __fp16*   Pw = (__fp16*)((char*)d_ws + (size_t)BATCH * SEQ * EMB * 2);

    qheads<<<BATCH * SEQ * NHEADS / 256, 256, 0, stream>>>(x, theta, H);
    qattn_mfma<<<128 * 16, 256, 0, stream>>>(H, Pw);
    proj_mfma<<<BATCH * SEQ / 16, 256, 0, stream>>>(Pw, W, bias, out);
}

// Round 17
// 89.858 us; speedup vs baseline: 1.5073x; 1.5073x over previous
//
#include <hip/hip_runtime.h>

#define NHEADS 16
#define NW 8
#define SEQ 1024
#define BATCH 8
#define EMB 128

typedef _Float16 half2_t __attribute__((ext_vector_type(2)));
typedef _Float16 half4_t __attribute__((ext_vector_type(4)));
typedef _Float16 half8_t __attribute__((ext_vector_type(8)));
typedef float    f32x4   __attribute__((ext_vector_type(4)));
typedef int      i32x2   __attribute__((ext_vector_type(2)));

__device__ __forceinline__ half2_t pkrtz(float a, float b) {
    return __builtin_bit_cast(half2_t, __builtin_amdgcn_cvt_pkrtz(a, b));
}

#if __has_builtin(__builtin_amdgcn_permlane16_swap)
#define HAVE_PLSWAP 1
#else
#define HAVE_PLSWAP 0
#endif

// qattn smem layout in halves (R14-proven):
//   kvh  [1024 keys][8 dims]      @ 0        (16 KB, row-major)
//   kvhT [8 dims][stride 1042]    @ 8192     (transposed; dword stride 521 == 9 mod 32)
//   ones [8] / zero [8]           @ 16528 / 16536
#define KVT       8192
#define KVT_STR   1042
#define ONES_OFF  (KVT + 8 * KVT_STR)      // 16528
#define ZERO_OFF  (ONES_OFF + 8)           // 16536
#define SMEM_H    (ZERO_OFF + 88)          // slack for last-iter prefetch overrun

// quantum_heads closed form for one (b,s,head) row (fp32 input):
// c[w] = cos(x[w] + theta[w]); z[0] = c1..c7; z[w>=1] = c0..cw
__device__ __forceinline__ void qrow(const float* __restrict__ xp,
                                     const float* __restrict__ th, float* z) {
    float4 a = *reinterpret_cast<const float4*>(xp);
    float4 b = *reinterpret_cast<const float4*>(xp + 4);
    float c0 = __cosf(a.x + th[0]);
    float c1 = __cosf(a.y + th[1]);
    float c2 = __cosf(a.z + th[2]);
    float c3 = __cosf(a.w + th[3]);
    float c4 = __cosf(b.x + th[4]);
    float c5 = __cosf(b.y + th[5]);
    float c6 = __cosf(b.z + th[6]);
    float c7 = __cosf(b.w + th[7]);
    float u = c1 * c2;
    u *= c3; u *= c4; u *= c5; u *= c6; u *= c7;
    z[0] = u;
    z[1] = c0 * c1;
    z[2] = z[1] * c2;
    z[3] = z[2] * c3;
    z[4] = z[3] * c4;
    z[5] = z[4] * c5;
    z[6] = z[5] * c6;
    z[7] = z[6] * c7;
}

// MFMA attention (R11/R14-verified layouts). 512-thread blocks: 8 waves/block,
// 33 KB LDS -> 4 blocks/CU -> 32 waves/CU (max occupancy, same LDS as R14).
// grid = 128 bh * 4 qsplits = 512 blocks; each wave: 2 q-tiles of 16.
__global__ __launch_bounds__(512, 8) void qattn_mfma(
    const float* __restrict__ x,
    const float* __restrict__ theta,
    __fp16* __restrict__ P)        // [B*S][128] f16, normalized attn@h
{
    __shared__ __align__(16) _Float16 smem[SMEM_H];
    const int t   = threadIdx.x;
    const int bid = blockIdx.x;
    const int qs  = bid & 3;                // query quarter (256 q)
    const int bh  = bid >> 2;               // 0..127
    const int b   = bh >> 4, h = bh & 15;

    float th[8];
#pragma unroll
    for (int w = 0; w < 8; ++w) th[w] = theta[w];   // wave-uniform -> s_loads

    // ---- stage all 1024 keys: row-major f16 + transposed copy (2/thread) ----
#pragma unroll
    for (int i = 0; i < 2; ++i) {
        const int kl = t + 512 * i;
        float z[8];
        qrow(x + ((size_t)(b * SEQ + kl) * EMB + h * NW), th, z);
        half8_t hv;
#pragma unroll
        for (int d = 0; d < 8; ++d) hv[d] = (_Float16)z[d];
        *reinterpret_cast<half8_t*>(&smem[kl * 8]) = hv;
#pragma unroll
        for (int d = 0; d < 8; ++d) smem[KVT + d * KVT_STR + kl] = hv[d];
    }
    if (t < 8)              smem[ONES_OFF + t]     = (_Float16)1.0f;
    else if (t < 16)        smem[ZERO_OFF + t - 8] = (_Float16)0.0f;
    __syncthreads();

    const int lane = t & 63;
    const int wv   = t >> 6;                // wave 0..7
    const int q16  = lane & 15;
    const int qd   = lane >> 4;             // quad 0..3
    const int qbase = qs * 256 + wv * 32;

    // ---- Q fragments (B operand): B[k=dim][n=q], quads!=0 read zeros ----
    const _Float16 QSh = (_Float16)0.51012924f;   // (1/sqrt(8))*log2(e)
    half8_t qfrag[2];
#pragma unroll
    for (int qi = 0; qi < 2; ++qi) {
        const _Float16* qp = (qd == 0)
            ? &smem[(qbase + qi * 16 + q16) * 8] : &smem[ZERO_OFF];
        half8_t qv = *reinterpret_cast<const half8_t*>(qp);
#pragma unroll
        for (int j = 0; j < 8; ++j) qv[j] = qv[j] * QSh;
        qfrag[qi] = qv;
    }

    // ---- loop-invariant pointers / lane constants ----
    const _Float16* ka = (qd == 0) ? &smem[q16 * 8]        : &smem[ZERO_OFF];
    const _Float16* kb = (qd == 0) ? &smem[(16 + q16) * 8] : &smem[ZERO_OFF];
    const int kstep = (qd == 0) ? 256 : 0;          // 32 keys * 8 halves

    // V-operand (A-op of PV MFMA) dword loads; key order kappa matches the
    // permlane-swap output (or consecutive for the bpermute fallback).
    const unsigned int* vb; int vo0, vo1, vo2, vo3; int vstep;
    if (q16 < 8) {
        vb = reinterpret_cast<const unsigned int*>(&smem[KVT + q16 * KVT_STR]);
#if HAVE_PLSWAP
        const int bo = (qd & 1) + (qd >> 1) * 4;
        vo0 = bo; vo1 = bo + 2; vo2 = bo + 8; vo3 = bo + 10;
#else
        vo0 = qd * 4; vo1 = vo0 + 1; vo2 = vo0 + 2; vo3 = vo0 + 3;
#endif
        vstep = 16;                                // 32 keys = 16 dwords
    } else if (q16 == 8) {
        vb = reinterpret_cast<const unsigned int*>(&smem[ONES_OFF]);
        vo0 = vo1 = vo2 = vo3 = 0; vstep = 0;
    } else {
        vb = reinterpret_cast<const unsigned int*>(&smem[ZERO_OFF]);
        vo0 = vo1 = vo2 = vo3 = 0; vstep = 0;
    }

#if !HAVE_PLSWAP
    const bool oddq = (qd & 1);
    const bool hiC  = (qd >= 2);
    const int  iA   = (q16 + (qd & 1) * 32 + (qd >> 1) * 16) * 4;
    const int  iB   = iA ^ 64;
#endif
    const int  lidx = (32 + q16) * 4;              // lane holding dim-8 row (l)

    f32x4 oacc[2] = {{0.f, 0.f, 0.f, 0.f}, {0.f, 0.f, 0.f, 0.f}};
    const f32x4 zc = {0.f, 0.f, 0.f, 0.f};

    half8_t kA = *reinterpret_cast<const half8_t*>(ka);
    half8_t kB = *reinterpret_cast<const half8_t*>(kb);
    unsigned int v0 = vb[vo0], v1 = vb[vo1], v2 = vb[vo2], v3 = vb[vo3];

    for (int kt = 0; kt < 32; ++kt) {
        ka += kstep; kb += kstep; vb += vstep;
        half8_t nkA = *reinterpret_cast<const half8_t*>(ka);   // prefetch (pad-safe)
        half8_t nkB = *reinterpret_cast<const half8_t*>(kb);
        unsigned int nv0 = vb[vo0], nv1 = vb[vo1], nv2 = vb[vo2], nv3 = vb[vo3];

        union { unsigned int i[4]; half8_t h; } vf;
        vf.i[0] = v0; vf.i[1] = v1; vf.i[2] = v2; vf.i[3] = v3;

#pragma unroll
        for (int qi = 0; qi < 2; ++qi) {
            // S^T tiles: C[row=key=qd*4+reg][col=q=lane&15]
            f32x4 c0 = __builtin_amdgcn_mfma_f32_16x16x32_f16(kA, qfrag[qi], zc, 0, 0, 0);
            f32x4 c1 = __builtin_amdgcn_mfma_f32_16x16x32_f16(kB, qfrag[qi], zc, 0, 0, 0);
            half2_t p0 = pkrtz(__builtin_amdgcn_exp2f(c0[0]), __builtin_amdgcn_exp2f(c0[1]));
            half2_t p1 = pkrtz(__builtin_amdgcn_exp2f(c0[2]), __builtin_amdgcn_exp2f(c0[3]));
            half2_t p2 = pkrtz(__builtin_amdgcn_exp2f(c1[0]), __builtin_amdgcn_exp2f(c1[1]));
            half2_t p3 = pkrtz(__builtin_amdgcn_exp2f(c1[2]), __builtin_amdgcn_exp2f(c1[3]));
            union { half2_t h; int i; } u0, u1, u2, u3;
            u0.h = p0; u1.h = p1; u2.h = p2; u3.h = p3;
            union { int i[4]; half8_t h; } bf;
#if HAVE_PLSWAP
            i32x2 s01 = __builtin_amdgcn_permlane16_swap(u0.i, u1.i, false, false);
            i32x2 s23 = __builtin_amdgcn_permlane16_swap(u2.i, u3.i, false, false);
            bf.i[0] = s01[0]; bf.i[1] = s01[1];
            bf.i[2] = s23[0]; bf.i[3] = s23[1];
#else
            const int a0 = oddq ? u2.i : u0.i;
            const int a1 = oddq ? u3.i : u1.i;
            const int a2 = oddq ? u0.i : u2.i;
            const int a3 = oddq ? u1.i : u3.i;
            const int r0 = __builtin_amdgcn_ds_bpermute(iA, a0);
            const int r1 = __builtin_amdgcn_ds_bpermute(iA, a1);
            const int r2 = __builtin_amdgcn_ds_bpermute(iB, a2);
            const int r3 = __builtin_amdgcn_ds_bpermute(iB, a3);
            bf.i[0] = hiC ? r2 : r0;
            bf.i[1] = hiC ? r3 : r1;
            bf.i[2] = hiC ? r0 : r2;
            bf.i[3] = hiC ? r1 : r3;
#endif
            // O^T += Vx^T . P^T  (ones col -> row-sum l in dim 8)
            oacc[qi] = __builtin_amdgcn_mfma_f32_16x16x32_f16(vf.h, bf.h, oacc[qi], 0, 0, 0);
        }
        kA = nkA; kB = nkB;
        v0 = nv0; v1 = nv1; v2 = nv2; v3 = nv3;
    }

    // ---- epilogue: normalize by l (row 8 = quad2 reg0), write P f16 ----
#pragma unroll
    for (int qi = 0; qi < 2; ++qi) {
        f32x4 c = oacc[qi];
        const float lsum = __int_as_float(
            __builtin_amdgcn_ds_bpermute(lidx, __float_as_int(c[0])));
        const float inv = 1.0f / lsum;
        if (qd < 2) {                       // quads 0,1 hold dims 0-7
            half2_t u0 = pkrtz(c[0] * inv, c[1] * inv);
            half2_t u1 = pkrtz(c[2] * inv, c[3] * inv);
            half4_t o4; o4[0] = u0[0]; o4[1] = u0[1]; o4[2] = u1[0]; o4[3] = u1[1];
            const int row = b * SEQ + qbase + qi * 16 + q16;
            *reinterpret_cast<half4_t*>(
                reinterpret_cast<_Float16*>(P) + (size_t)row * EMB + h * NW + qd * 4) = o4;
        }
    }
}

// MFMA projection with fused W f32->f16 conversion (R12-verified):
// out[row][e] = sum_f P[row][f]*W[e][f] + bias[e]. No LDS, no barriers.
__global__ __launch_bounds__(256) void proj_mfma(
    const __fp16* __restrict__ Pv,
    const float* __restrict__ W,
    const float* __restrict__ bias,
    float* __restrict__ out)
{
    const _Float16* P = reinterpret_cast<const _Float16*>(Pv);
    const int t    = threadIdx.x;
    const int lane = t & 63;
    const int wv   = t >> 6;
    const int n16  = lane & 15;
    const int qd   = lane >> 4;
    const int row0 = blockIdx.x * 16;
    const int col0 = wv * 32;

    half8_t a[4];
#pragma unroll
    for (int kb = 0; kb < 4; ++kb)
        a[kb] = *reinterpret_cast<const half8_t*>(
            P + (size_t)(row0 + n16) * EMB + kb * 32 + qd * 8);

    const f32x4 zc = {0.f, 0.f, 0.f, 0.f};
#pragma unroll
    for (int et = 0; et < 2; ++et) {
        const int e = col0 + et * 16 + n16;
        f32x4 acc = zc;
#pragma unroll
        for (int kb = 0; kb < 4; ++kb) {
            const float* wp = W + (size_t)e * EMB + kb * 32 + qd * 8;
            float4 w0 = *reinterpret_cast<const float4*>(wp);
            float4 w1 = *reinterpret_cast<const float4*>(wp + 4);
            half2_t h0 = pkrtz(w0.x, w0.y);
            half2_t h1 = pkrtz(w0.z, w0.w);
            half2_t h2 = pkrtz(w1.x, w1.y);
            half2_t h3 = pkrtz(w1.z, w1.w);
            half8_t bfr;
            bfr[0] = h0[0]; bfr[1] = h0[1]; bfr[2] = h1[0]; bfr[3] = h1[1];
            bfr[4] = h2[0]; bfr[5] = h2[1]; bfr[6] = h3[0]; bfr[7] = h3[1];
            acc = __builtin_amdgcn_mfma_f32_16x16x32_f16(a[kb], bfr, acc, 0, 0, 0);
        }
        const float bv = bias[e];
#pragma unroll
        for (int r = 0; r < 4; ++r)
            out[(size_t)(row0 + qd * 4 + r) * EMB + e] = acc[r] + bv;
    }
}

extern "C" void kernel_launch(void* const* d_in, const int* in_sizes, int n_in,
                              void* d_out, int out_size, void* d_ws, size_t ws_size,
                              hipStream_t stream)
{
    const float* x     = (const float*)d_in[0];
    const float* theta = (const float*)d_in[1];
    const float* W     = (const float*)d_in[2];
    const float* bias  = (const float*)d_in[3];
    float* out = (float*)d_out;

    __fp16* Pw = (__fp16*)d_ws;                              // 2 MB

    qattn_mfma<<<128 * 4, 512, 0, stream>>>(x, theta, Pw);
    proj_mfma<<<BATCH * SEQ / 16, 256, 0, stream>>>(Pw, W, bias, out);
}